// Round 4
// baseline (851.585 us; speedup 1.0000x reference)
//
#include <hip/hip_runtime.h>
#include <hip/hip_cooperative_groups.h>
#include <math.h>

namespace cg = cooperative_groups;

#define DEV __device__ __forceinline__

// Soft gate: c0 + ca*a + cb*b + cab*(a*b)
DEV float gev(float4 c, float a, float b) {
    return fmaf(c.w, a * b, fmaf(c.z, b, fmaf(c.y, a, c.x)));
}

DEV float sel4(const float h[4], int i) {
    float r = h[0];
    r = (i == 1) ? h[1] : r;
    r = (i == 2) ? h[2] : r;
    r = (i == 3) ? h[3] : r;
    return r;
}

DEV float sel2(const float h[2], int i) { return (i == 1) ? h[1] : h[0]; }

struct Params {
    const float* x;
    const int *c1i0, *c1i1, *c1i2;
    const int *c2i0, *c2i1, *c2i2;
    const int *c3i0, *c3i1, *c3i2;
    const int *fc1i, *fc2i, *fc3i;
    const float *w0, *w1, *w2, *w3, *w4, *w5, *w6, *w7, *w8, *w9, *w10, *w11;
    float4* coef;
    float *xb, *p1, *p2, *p3, *f1, *f2, *f3, *out;
};

// ---------------------------------------------------------------------------
// One conv output item (batch-major): rec = f*HP*HP + ph*HP + pw, lane = b.
// in: [CIN*HIN*HIN][128], out: [F*HP*HP][128].  Metadata wave-uniform.
// ---------------------------------------------------------------------------
template <int CIN, int KS, int PAD, int HIN, int F>
DEV void conv_item(int rec, int b, const float* __restrict__ in,
                   const int* __restrict__ idx0, const int* __restrict__ idx1,
                   const int* __restrict__ idx2,
                   const float4* __restrict__ cf0, const float4* __restrict__ cf1,
                   const float4* __restrict__ cf2, float* __restrict__ out)
{
    constexpr int HP = (HIN + 2 * PAD - KS + 1) / 2;
    int pw = rec % HP;
    int ph = (rec / HP) % HP;
    int f  = rec / (HP * HP);

    int a0[4], b0[4];
    #pragma unroll
    for (int g = 0; g < 4; g++) { a0[g] = idx0[f*4+g]; b0[g] = idx0[F*4 + f*4+g]; }
    int a1[2], b1[2];
    #pragma unroll
    for (int g = 0; g < 2; g++) { a1[g] = idx1[f*2+g]; b1[g] = idx1[F*2 + f*2+g]; }
    int a2 = idx2[f], b2 = idx2[F + f];
    float4 C0[4] = {cf0[f*4], cf0[f*4+1], cf0[f*4+2], cf0[f*4+3]};
    float4 C1[2] = {cf1[f*2], cf1[f*2+1]};
    float4 C2 = cf2[f];

    float m = -1e30f;
    #pragma unroll
    for (int dy = 0; dy < 2; dy++) {
        #pragma unroll
        for (int dx = 0; dx < 2; dx++) {
            int oh = 2 * ph + dy, ow = 2 * pw + dx;
            float h0[4];
            #pragma unroll
            for (int g = 0; g < 4; g++) {
                float va, vb;
                {
                    int tt = a0[g];
                    int c = tt / (KS * KS), r = tt % (KS * KS);
                    int y = oh + r / KS - PAD, xx = ow + r % KS - PAD;
                    bool ok = (PAD == 0) || (y >= 0 && y < HIN && xx >= 0 && xx < HIN);
                    va = ok ? in[((c * HIN + y) * HIN + xx) * 128 + b] : 0.f;
                }
                {
                    int tt = b0[g];
                    int c = tt / (KS * KS), r = tt % (KS * KS);
                    int y = oh + r / KS - PAD, xx = ow + r % KS - PAD;
                    bool ok = (PAD == 0) || (y >= 0 && y < HIN && xx >= 0 && xx < HIN);
                    vb = ok ? in[((c * HIN + y) * HIN + xx) * 128 + b] : 0.f;
                }
                h0[g] = gev(C0[g], va, vb);
            }
            float h1[2];
            #pragma unroll
            for (int g = 0; g < 2; g++)
                h1[g] = gev(C1[g], sel4(h0, a1[g]), sel4(h0, b1[g]));
            float v = gev(C2, sel2(h1, a2), sel2(h1, b2));
            m = fmaxf(m, v);
        }
    }
    out[rec * 128 + b] = m;
}

// ---------------------------------------------------------------------------
// Whole network in ONE cooperative kernel.  Stages separated by grid.sync().
// Gate coef segments (float4 offsets): c1L0 0(64) c1L1 64(32) c1L2 96(16)
// c2L0 112(192) c2L1 304(96) c2L2 400(48) c3L0 448(576) c3L1 1024(288)
// c3L2 1312(144) fc1 1456(20480) fc2 21936(10240) fc3 32176(5120).
// Grid = 512 blocks x 256 thr: 2 blocks/CU co-resident at <=256 VGPR
// (__launch_bounds__(256,2)), safe for cooperative launch.
// ---------------------------------------------------------------------------
__global__ __launch_bounds__(256, 2) void fused_all(Params P)
{
    cg::grid_group grid = cg::this_grid();
    const int tid = blockIdx.x * 256 + threadIdx.x;
    const int NT  = gridDim.x * 256;

    // ---- stage 0: coef (37296) | binarize+transpose (100352) | zero out (1000)
    for (int t = tid; t < 138648; t += NT) {
        if (t < 37296) {
            const float* wrow;
            if      (t < 64)    wrow = P.w0  + t * 16;
            else if (t < 96)    wrow = P.w1  + (t - 64) * 16;
            else if (t < 112)   wrow = P.w2  + (t - 96) * 16;
            else if (t < 304)   wrow = P.w3  + (t - 112) * 16;
            else if (t < 400)   wrow = P.w4  + (t - 304) * 16;
            else if (t < 448)   wrow = P.w5  + (t - 400) * 16;
            else if (t < 1024)  wrow = P.w6  + (t - 448) * 16;
            else if (t < 1312)  wrow = P.w7  + (t - 1024) * 16;
            else if (t < 1456)  wrow = P.w8  + (t - 1312) * 16;
            else if (t < 21936) wrow = P.w9  + (t - 1456) * 16;
            else if (t < 32176) wrow = P.w10 + (t - 21936) * 16;
            else                wrow = P.w11 + (t - 32176) * 16;
            const float4* wv = (const float4*)wrow;
            float4 q0 = wv[0], q1 = wv[1], q2 = wv[2], q3 = wv[3];
            float p[16] = {q0.x,q0.y,q0.z,q0.w, q1.x,q1.y,q1.z,q1.w,
                           q2.x,q2.y,q2.z,q2.w, q3.x,q3.y,q3.z,q3.w};
            float mx = p[0];
            #pragma unroll
            for (int k = 1; k < 16; k++) mx = fmaxf(mx, p[k]);
            float s = 0.f;
            #pragma unroll
            for (int k = 0; k < 16; k++) { p[k] = __expf(p[k] - mx); s += p[k]; }
            float inv = 1.f / s;
            #pragma unroll
            for (int k = 0; k < 16; k++) p[k] *= inv;
            float c0  = p[8]+p[9]+p[10]+p[11]+p[12]+p[13]+p[14]+p[15];
            float ca  = p[2]+p[3]+p[6]+p[7]-p[8]-p[9]-p[12]-p[13];
            float cb  = p[4]+p[5]+p[6]+p[7]-p[8]-p[9]-p[10]-p[11];
            float cab = p[1]-p[2]-p[4]-2.f*p[6]-p[7]+p[8]+2.f*p[9]+p[11]+p[13]-p[14];
            P.coef[t] = make_float4(c0, ca, cb, cab);
        } else if (t < 137648) {
            int u = t - 37296;
            int b = u & 127, pix = u >> 7;
            float v = (b < 100) ? P.x[b * 784 + pix] : 0.f;
            P.xb[pix * 128 + b] = v > 0.5f ? 1.f : 0.f;
        } else {
            P.out[t - 137648] = 0.f;
        }
    }
    __threadfence();
    grid.sync();

    // ---- stage 1: c1 conv5 pad0 28->24 pool->12: xb -> p1 [2304][128]
    for (int t = tid; t < 2304 * 128; t += NT)
        conv_item<1, 5, 0, 28, 16>(t >> 7, t & 127, P.xb, P.c1i0, P.c1i1, P.c1i2,
                                   P.coef + 0, P.coef + 64, P.coef + 96, P.p1);
    __threadfence();
    grid.sync();

    // ---- stage 2: c2 conv3 pad1 12->12 pool->6: p1 -> p2 [1728][128]
    for (int t = tid; t < 1728 * 128; t += NT)
        conv_item<16, 3, 1, 12, 48>(t >> 7, t & 127, P.p1, P.c2i0, P.c2i1, P.c2i2,
                                    P.coef + 112, P.coef + 304, P.coef + 400, P.p2);
    __threadfence();
    grid.sync();

    // ---- stage 3: c3 conv3 pad1 6->6 pool->3: p2 -> p3 [1296][128]
    for (int t = tid; t < 1296 * 128; t += NT)
        conv_item<48, 3, 1, 6, 144>(t >> 7, t & 127, P.p2, P.c3i0, P.c3i1, P.c3i2,
                                    P.coef + 448, P.coef + 1024, P.coef + 1312, P.p3);
    __threadfence();
    grid.sync();

    // ---- stage 4: fc1 1296 -> 20480
    for (int t = tid; t < 20480 * 128; t += NT) {
        int b = t & 127, o = t >> 7;
        int ia = P.fc1i[o], ib = P.fc1i[20480 + o];
        P.f1[t] = gev(P.coef[1456 + o], P.p3[ia * 128 + b], P.p3[ib * 128 + b]);
    }
    __threadfence();
    grid.sync();

    // ---- stage 5: fc2 20480 -> 10240
    for (int t = tid; t < 10240 * 128; t += NT) {
        int b = t & 127, o = t >> 7;
        int ia = P.fc2i[o], ib = P.fc2i[10240 + o];
        P.f2[t] = gev(P.coef[21936 + o], P.f1[ia * 128 + b], P.f1[ib * 128 + b]);
    }
    __threadfence();
    grid.sync();

    // ---- stage 6: fc3 10240 -> 5120
    for (int t = tid; t < 5120 * 128; t += NT) {
        int b = t & 127, o = t >> 7;
        int ia = P.fc3i[o], ib = P.fc3i[5120 + o];
        P.f3[t] = gev(P.coef[32176 + o], P.f2[ia * 128 + b], P.f2[ib * 128 + b]);
    }
    __threadfence();
    grid.sync();

    // ---- stage 7: GroupSum, chunked: 10 groups x 128 b x 8 chunks of 64
    for (int t = tid; t < 10240; t += NT) {
        int b = t & 127;
        int r = t >> 7;
        int g = r % 10, chunk = r / 10;
        if (b < 100) {
            const float* p = P.f3 + (g * 512 + chunk * 64) * 128 + b;
            float s = 0.f;
            #pragma unroll
            for (int i = 0; i < 64; i++) s += p[i * 128];
            atomicAdd(&P.out[b * 10 + g], s * (1.f / 30.f));
        }
    }
}

extern "C" void kernel_launch(void* const* d_in, const int* in_sizes, int n_in,
                              void* d_out, int out_size, void* d_ws, size_t ws_size,
                              hipStream_t stream)
{
    Params P;
    P.x    = (const float*)d_in[0];
    P.c1i0 = (const int*)d_in[1];  P.w0  = (const float*)d_in[2];
    P.c1i1 = (const int*)d_in[3];  P.w1  = (const float*)d_in[4];
    P.c1i2 = (const int*)d_in[5];  P.w2  = (const float*)d_in[6];
    P.c2i0 = (const int*)d_in[7];  P.w3  = (const float*)d_in[8];
    P.c2i1 = (const int*)d_in[9];  P.w4  = (const float*)d_in[10];
    P.c2i2 = (const int*)d_in[11]; P.w5  = (const float*)d_in[12];
    P.c3i0 = (const int*)d_in[13]; P.w6  = (const float*)d_in[14];
    P.c3i1 = (const int*)d_in[15]; P.w7  = (const float*)d_in[16];
    P.c3i2 = (const int*)d_in[17]; P.w8  = (const float*)d_in[18];
    P.fc1i = (const int*)d_in[19]; P.w9  = (const float*)d_in[20];
    P.fc2i = (const int*)d_in[21]; P.w10 = (const float*)d_in[22];
    P.fc3i = (const int*)d_in[23]; P.w11 = (const float*)d_in[24];

    // ws layout (bytes, 16B-aligned):
    //   coef @ 0        : 37296*16        = 596736
    //   xb   @ 596736   : 784*128*4       = 401408
    //   p1   @ 998144   : 2304*128*4      = 1179648
    //   p2   @ 2177792  : 1728*128*4      = 884736
    //   p3   @ 3062528  : 1296*128*4      = 663552
    //   f1   @ 3726080  : 20480*128*4     = 10485760
    //   f2   @ 14211840 : 10240*128*4     = 5242880
    //   f3   @ 19454720 : 5120*128*4      = 2621440   (end 22076160)
    char* ws = (char*)d_ws;
    P.coef = (float4*)ws;
    P.xb = (float*)(ws + 596736);
    P.p1 = (float*)(ws + 998144);
    P.p2 = (float*)(ws + 2177792);
    P.p3 = (float*)(ws + 3062528);
    P.f1 = (float*)(ws + 3726080);
    P.f2 = (float*)(ws + 14211840);
    P.f3 = (float*)(ws + 19454720);
    P.out = (float*)d_out;

    void* args[] = {&P};
    hipLaunchCooperativeKernel((const void*)fused_all, dim3(512), dim3(256),
                               args, 0, stream);
}

// Round 5
// 144.359 us; speedup vs baseline: 5.8991x; 5.8991x over previous
//
#include <hip/hip_runtime.h>
#include <hip/hip_fp16.h>
#include <math.h>

#define DEV __device__ __forceinline__

// Soft gate: c0 + ca*a + cb*b + cab*(a*b)
DEV float gev(float4 c, float a, float b) {
    return fmaf(c.w, a * b, fmaf(c.z, b, fmaf(c.y, a, c.x)));
}

DEV float sel4(const float h[4], int i) {
    float r = h[0];
    r = (i == 1) ? h[1] : r;
    r = (i == 2) ? h[2] : r;
    r = (i == 3) ? h[3] : r;
    return r;
}

DEV float sel2(const float h[2], int i) { return (i == 1) ? h[1] : h[0]; }

// ---------------------------------------------------------------------------
// setup: per-gate affine coefficients (softmax over 16 ops -> {c0,ca,cb,cab}).
// Segments (cumulative float4 offsets): c1L0 0(64) c1L1 64(32) c1L2 96(16)
// c2L0 112(192) c2L1 304(96) c2L2 400(48) c3L0 448(576) c3L1 1024(288)
// c3L2 1312(144) fc1 1456(20480) fc2 21936(10240) fc3 32176(5120). Tot 37296.
// ---------------------------------------------------------------------------
__global__ __launch_bounds__(256) void coef_kernel(
    const float* __restrict__ w0, const float* __restrict__ w1,
    const float* __restrict__ w2, const float* __restrict__ w3,
    const float* __restrict__ w4, const float* __restrict__ w5,
    const float* __restrict__ w6, const float* __restrict__ w7,
    const float* __restrict__ w8, const float* __restrict__ w9,
    const float* __restrict__ w10, const float* __restrict__ w11,
    float4* __restrict__ coef)
{
    int t = blockIdx.x * 256 + threadIdx.x;
    if (t >= 37296) return;
    const float* wrow;
    if      (t < 64)    wrow = w0  + t * 16;
    else if (t < 96)    wrow = w1  + (t - 64) * 16;
    else if (t < 112)   wrow = w2  + (t - 96) * 16;
    else if (t < 304)   wrow = w3  + (t - 112) * 16;
    else if (t < 400)   wrow = w4  + (t - 304) * 16;
    else if (t < 448)   wrow = w5  + (t - 400) * 16;
    else if (t < 1024)  wrow = w6  + (t - 448) * 16;
    else if (t < 1312)  wrow = w7  + (t - 1024) * 16;
    else if (t < 1456)  wrow = w8  + (t - 1312) * 16;
    else if (t < 21936) wrow = w9  + (t - 1456) * 16;
    else if (t < 32176) wrow = w10 + (t - 21936) * 16;
    else                wrow = w11 + (t - 32176) * 16;

    const float4* wv = (const float4*)wrow;
    float4 q0 = wv[0], q1 = wv[1], q2 = wv[2], q3 = wv[3];
    float p[16] = {q0.x,q0.y,q0.z,q0.w, q1.x,q1.y,q1.z,q1.w,
                   q2.x,q2.y,q2.z,q2.w, q3.x,q3.y,q3.z,q3.w};
    float mx = p[0];
    #pragma unroll
    for (int k = 1; k < 16; k++) mx = fmaxf(mx, p[k]);
    float s = 0.f;
    #pragma unroll
    for (int k = 0; k < 16; k++) { p[k] = __expf(p[k] - mx); s += p[k]; }
    float inv = 1.f / s;
    #pragma unroll
    for (int k = 0; k < 16; k++) p[k] *= inv;

    float c0  = p[8]+p[9]+p[10]+p[11]+p[12]+p[13]+p[14]+p[15];
    float ca  = p[2]+p[3]+p[6]+p[7]-p[8]-p[9]-p[12]-p[13];
    float cb  = p[4]+p[5]+p[6]+p[7]-p[8]-p[9]-p[10]-p[11];
    float cab = p[1]-p[2]-p[4]-2.f*p[6]-p[7]+p[8]+2.f*p[9]+p[11]+p[13]-p[14];
    coef[t] = make_float4(c0, ca, cb, cab);
}

// ---------------------------------------------------------------------------
// Conv stage (in-LDS): logic-tree conv + orpool; Sin [CIN][HIN][HIN],
// Sout [F][HP][HP].  1024-thread strided over records.
// ---------------------------------------------------------------------------
template <int CIN, int KS, int PAD, int HIN, int F>
DEV void conv_stage(const float* Sin, float* Sout,
                    const int* __restrict__ idx0, const int* __restrict__ idx1,
                    const int* __restrict__ idx2,
                    const float4* __restrict__ cf0, const float4* __restrict__ cf1,
                    const float4* __restrict__ cf2, int tid)
{
    constexpr int HP = (HIN + 2 * PAD - KS + 1) / 2;
    for (int t = tid; t < F * HP * HP; t += 1024) {
        int pw = t % HP;
        int ph = (t / HP) % HP;
        int f  = t / (HP * HP);

        int a0[4], b0[4];
        #pragma unroll
        for (int g = 0; g < 4; g++) { a0[g] = idx0[f*4+g]; b0[g] = idx0[F*4 + f*4+g]; }
        int a1[2], b1[2];
        #pragma unroll
        for (int g = 0; g < 2; g++) { a1[g] = idx1[f*2+g]; b1[g] = idx1[F*2 + f*2+g]; }
        int a2 = idx2[f], b2 = idx2[F + f];
        float4 C0[4] = {cf0[f*4], cf0[f*4+1], cf0[f*4+2], cf0[f*4+3]};
        float4 C1[2] = {cf1[f*2], cf1[f*2+1]};
        float4 C2 = cf2[f];

        float m = -1e30f;
        #pragma unroll
        for (int dy = 0; dy < 2; dy++) {
            #pragma unroll
            for (int dx = 0; dx < 2; dx++) {
                int oh = 2 * ph + dy, ow = 2 * pw + dx;
                float va[4], vb[4];
                #pragma unroll
                for (int g = 0; g < 4; g++) {
                    int tt = a0[g];
                    int c = tt / (KS * KS), r = tt % (KS * KS);
                    int y = oh + r / KS - PAD, xx = ow + r % KS - PAD;
                    bool ok = (PAD == 0) || (y >= 0 && y < HIN && xx >= 0 && xx < HIN);
                    va[g] = ok ? Sin[(c * HIN + y) * HIN + xx] : 0.f;
                }
                #pragma unroll
                for (int g = 0; g < 4; g++) {
                    int tt = b0[g];
                    int c = tt / (KS * KS), r = tt % (KS * KS);
                    int y = oh + r / KS - PAD, xx = ow + r % KS - PAD;
                    bool ok = (PAD == 0) || (y >= 0 && y < HIN && xx >= 0 && xx < HIN);
                    vb[g] = ok ? Sin[(c * HIN + y) * HIN + xx] : 0.f;
                }
                float h0[4];
                #pragma unroll
                for (int g = 0; g < 4; g++) h0[g] = gev(C0[g], va[g], vb[g]);
                float h1[2];
                #pragma unroll
                for (int g = 0; g < 2; g++)
                    h1[g] = gev(C1[g], sel4(h0, a1[g]), sel4(h0, b1[g]));
                float v = gev(C2, sel2(h1, a2), sel2(h1, b2));
                m = fmaxf(m, v);
            }
        }
        Sout[t] = m;
    }
}

// ---------------------------------------------------------------------------
// FC stage (in-LDS), chunk-of-5 software pipeline: 15 independent global
// metadata loads -> 10 LDS gathers -> 5 gate evals.  DOUT % (1024*5) == 0
// for fc1/fc2/fc3 (20480, 10240, 5120).
// ---------------------------------------------------------------------------
template <int DOUT, typename TIN, typename TOUT>
DEV void fc_stage(const TIN* Sin, TOUT* Sout, const int* __restrict__ idx,
                  const float4* __restrict__ cf, int tid)
{
    constexpr int K = DOUT / 1024;   // evals per thread: 20 / 10 / 5
    #pragma unroll 1
    for (int k0 = 0; k0 < K; k0 += 5) {
        int ia[5], ib[5];
        float4 c[5];
        #pragma unroll
        for (int j = 0; j < 5; j++) {
            int o = tid + (k0 + j) * 1024;
            ia[j] = idx[o];
            ib[j] = idx[DOUT + o];
            c[j]  = cf[o];
        }
        float va[5], vb[5];
        #pragma unroll
        for (int j = 0; j < 5; j++) {
            va[j] = (float)Sin[ia[j]];
            vb[j] = (float)Sin[ib[j]];
        }
        #pragma unroll
        for (int j = 0; j < 5; j++) {
            int o = tid + (k0 + j) * 1024;
            Sout[o] = (TOUT)gev(c[j], va[j], vb[j]);
        }
    }
}

// ---------------------------------------------------------------------------
// Whole network, one WG per batch element, 1024 threads (16 waves/CU).
// Aliased LDS (bytes):
//   XB [0,3136) | P1 [3136,12352) | P2 [12352,19264) | P3 [19264,24448)
//   F1 fp16 [24448,65408) | F2 fp16 [0,20480) | F3 fp32 [24448,44928)
// peak live = fc2 (F1+F2) = 60 KiB; alloc 65408 B < 64 KiB static limit.
// ---------------------------------------------------------------------------
__global__ __launch_bounds__(1024, 1) void fused_net(
    const float* __restrict__ x,
    const int* __restrict__ c1i0, const int* __restrict__ c1i1, const int* __restrict__ c1i2,
    const int* __restrict__ c2i0, const int* __restrict__ c2i1, const int* __restrict__ c2i2,
    const int* __restrict__ c3i0, const int* __restrict__ c3i1, const int* __restrict__ c3i2,
    const int* __restrict__ fc1i, const int* __restrict__ fc2i, const int* __restrict__ fc3i,
    const float4* __restrict__ coef,
    float* __restrict__ out)
{
    __shared__ __align__(16) char S[65408];
    float*  XB = (float*)S;                 // 784
    float*  P1 = (float*)S + 784;           // 2304 (16x12x12)
    float*  P2 = (float*)S + 3088;          // 1728 (48x6x6)
    float*  P3 = (float*)S + 4816;          // 1296 (144x3x3)
    __half* F1 = (__half*)(S + 24448);      // 20480
    __half* F2 = (__half*)(S + 0);          // 10240
    float*  F3 = (float*)(S + 24448);       // 5120

    const int b = blockIdx.x, tid = threadIdx.x;
    const float* xb = x + b * 784;
    if (tid < 784) XB[tid] = xb[tid] > 0.5f ? 1.f : 0.f;
    __syncthreads();

    conv_stage<1, 5, 0, 28, 16>(XB, P1, c1i0, c1i1, c1i2,
                                coef + 0, coef + 64, coef + 96, tid);
    __syncthreads();
    conv_stage<16, 3, 1, 12, 48>(P1, P2, c2i0, c2i1, c2i2,
                                 coef + 112, coef + 304, coef + 400, tid);
    __syncthreads();
    conv_stage<48, 3, 1, 6, 144>(P2, P3, c3i0, c3i1, c3i2,
                                 coef + 448, coef + 1024, coef + 1312, tid);
    __syncthreads();

    fc_stage<20480>(P3, F1, fc1i, coef + 1456, tid);
    __syncthreads();
    fc_stage<10240>(F1, F2, fc2i, coef + 21936, tid);
    __syncthreads();
    fc_stage<5120>(F2, F3, fc3i, coef + 32176, tid);
    __syncthreads();

    // GroupSum: waves 0..9 each reduce one group of 512, write out[b*10+g].
    int wave = tid >> 6, lane = tid & 63;
    if (wave < 10) {
        float s = 0.f;
        #pragma unroll
        for (int i = 0; i < 8; i++) s += F3[wave * 512 + i * 64 + lane];
        #pragma unroll
        for (int off = 32; off > 0; off >>= 1) s += __shfl_down(s, off, 64);
        if (lane == 0) out[b * 10 + wave] = s * (1.f / 30.f);
    }
}

extern "C" void kernel_launch(void* const* d_in, const int* in_sizes, int n_in,
                              void* d_out, int out_size, void* d_ws, size_t ws_size,
                              hipStream_t stream)
{
    const float* x     = (const float*)d_in[0];
    const int*   c1i0  = (const int*)d_in[1];  const float* c1w0 = (const float*)d_in[2];
    const int*   c1i1  = (const int*)d_in[3];  const float* c1w1 = (const float*)d_in[4];
    const int*   c1i2  = (const int*)d_in[5];  const float* c1w2 = (const float*)d_in[6];
    const int*   c2i0  = (const int*)d_in[7];  const float* c2w0 = (const float*)d_in[8];
    const int*   c2i1  = (const int*)d_in[9];  const float* c2w1 = (const float*)d_in[10];
    const int*   c2i2  = (const int*)d_in[11]; const float* c2w2 = (const float*)d_in[12];
    const int*   c3i0  = (const int*)d_in[13]; const float* c3w0 = (const float*)d_in[14];
    const int*   c3i1  = (const int*)d_in[15]; const float* c3w1 = (const float*)d_in[16];
    const int*   c3i2  = (const int*)d_in[17]; const float* c3w2 = (const float*)d_in[18];
    const int*   fc1i  = (const int*)d_in[19]; const float* fc1w = (const float*)d_in[20];
    const int*   fc2i  = (const int*)d_in[21]; const float* fc2w = (const float*)d_in[22];
    const int*   fc3i  = (const int*)d_in[23]; const float* fc3w = (const float*)d_in[24];

    float4* coef = (float4*)d_ws;   // 37296 * 16 B = 596,736 B

    coef_kernel<<<146, 256, 0, stream>>>(
        c1w0, c1w1, c1w2, c2w0, c2w1, c2w2, c3w0, c3w1, c3w2,
        fc1w, fc2w, fc3w, coef);

    fused_net<<<100, 1024, 0, stream>>>(
        x,
        c1i0, c1i1, c1i2, c2i0, c2i1, c2i2, c3i0, c3i1, c3i2,
        fc1i, fc2i, fc3i, coef, (float*)d_out);
}

// Round 6
// 134.668 us; speedup vs baseline: 6.3236x; 1.0720x over previous
//
#include <hip/hip_runtime.h>
#include <hip/hip_fp16.h>
#include <math.h>

#define DEV __device__ __forceinline__

// Soft gate: c0 + ca*a + cb*b + cab*(a*b)
DEV float gev(float4 c, float a, float b) {
    return fmaf(c.w, a * b, fmaf(c.z, b, fmaf(c.y, a, c.x)));
}

// softmax over 16 op-logits -> affine coefficients {c0, ca, cb, cab}
DEV float4 softmax_coef(const float* __restrict__ wrow) {
    const float4* wv = (const float4*)wrow;
    float4 q0 = wv[0], q1 = wv[1], q2 = wv[2], q3 = wv[3];
    float p[16] = {q0.x,q0.y,q0.z,q0.w, q1.x,q1.y,q1.z,q1.w,
                   q2.x,q2.y,q2.z,q2.w, q3.x,q3.y,q3.z,q3.w};
    float mx = p[0];
    #pragma unroll
    for (int k = 1; k < 16; k++) mx = fmaxf(mx, p[k]);
    float s = 0.f;
    #pragma unroll
    for (int k = 0; k < 16; k++) { p[k] = __expf(p[k] - mx); s += p[k]; }
    float inv = 1.f / s;
    #pragma unroll
    for (int k = 0; k < 16; k++) p[k] *= inv;
    float c0  = p[8]+p[9]+p[10]+p[11]+p[12]+p[13]+p[14]+p[15];
    float ca  = p[2]+p[3]+p[6]+p[7]-p[8]-p[9]-p[12]-p[13];
    float cb  = p[4]+p[5]+p[6]+p[7]-p[8]-p[9]-p[10]-p[11];
    float cab = p[1]-p[2]-p[4]-2.f*p[6]-p[7]+p[8]+2.f*p[9]+p[11]+p[13]-p[14];
    return make_float4(c0, ca, cb, cab);
}

DEV float4 onehot4(int i) {
    return make_float4(i == 0 ? 1.f : 0.f, i == 1 ? 1.f : 0.f,
                       i == 2 ? 1.f : 0.f, i == 3 ? 1.f : 0.f);
}

// ---------------------------------------------------------------------------
// setup_kernel: compiles the network into packed per-gate / per-filter
// records so the hot kernel does contiguous dwordx4 metadata loads only.
//   t in [0,20480)        : fc1 gate -> 32B record {coef4 | ia,ib,-,-}
//   t in [20480,30720)    : fc2 gate
//   t in [30720,35840)    : fc3 gate
//   t in [35840,36048)    : conv filter (16 c1 | 48 c2 | 144 c3) -> 224B:
//     [0] int4 a-offsets (pre-decoded padded-LDS base offsets)
//     [1] int4 b-offsets
//     [2..5]  float4 coef L0 gates 0..3
//     [6..9]  float4 one-hot selectors: a1[0], b1[0], a1[1], b1[1]
//     [10,11] float4 coef L1 gates 0,1
//     [12]    float4 {a2==0, a2==1, b2==0, b2==1}
//     [13]    float4 coef L2
// ---------------------------------------------------------------------------
__global__ __launch_bounds__(256) void setup_kernel(
    const int* __restrict__ c1i0, const int* __restrict__ c1i1, const int* __restrict__ c1i2,
    const int* __restrict__ c2i0, const int* __restrict__ c2i1, const int* __restrict__ c2i2,
    const int* __restrict__ c3i0, const int* __restrict__ c3i1, const int* __restrict__ c3i2,
    const float* __restrict__ c1w0, const float* __restrict__ c1w1, const float* __restrict__ c1w2,
    const float* __restrict__ c2w0, const float* __restrict__ c2w1, const float* __restrict__ c2w2,
    const float* __restrict__ c3w0, const float* __restrict__ c3w1, const float* __restrict__ c3w2,
    const int* __restrict__ fc1i, const float* __restrict__ fc1w,
    const int* __restrict__ fc2i, const float* __restrict__ fc2w,
    const int* __restrict__ fc3i, const float* __restrict__ fc3w,
    float4* __restrict__ fcp1, float4* __restrict__ fcp2, float4* __restrict__ fcp3,
    float4* __restrict__ cvp)
{
    int t = blockIdx.x * 256 + threadIdx.x;
    if (t >= 36048) return;
    if (t < 35840) {
        const float* w; const int* idx; float4* dst; int o, D;
        if (t < 20480)      { o = t;         D = 20480; w = fc1w; idx = fc1i; dst = fcp1; }
        else if (t < 30720) { o = t - 20480; D = 10240; w = fc2w; idx = fc2i; dst = fcp2; }
        else                { o = t - 30720; D = 5120;  w = fc3w; idx = fc3i; dst = fcp3; }
        dst[2 * o] = softmax_coef(w + o * 16);
        int4 ii = make_int4(idx[o], idx[D + o], 0, 0);
        ((int4*)dst)[2 * o + 1] = ii;
        return;
    }
    // conv filter pack
    int f = t - 35840;               // 0..207
    const int *i0, *i1, *i2; const float *W0, *W1, *W2;
    int F, KS, mode, lf;
    if (f < 16)      { lf = f;      F = 16;  KS = 5; mode = 1;
                       i0 = c1i0; i1 = c1i1; i2 = c1i2; W0 = c1w0; W1 = c1w1; W2 = c1w2; }
    else if (f < 64) { lf = f - 16; F = 48;  KS = 3; mode = 2;
                       i0 = c2i0; i1 = c2i1; i2 = c2i2; W0 = c2w0; W1 = c2w1; W2 = c2w2; }
    else             { lf = f - 64; F = 144; KS = 3; mode = 3;
                       i0 = c3i0; i1 = c3i1; i2 = c3i2; W0 = c3w0; W1 = c3w1; W2 = c3w2; }
    float4* pk = cvp + f * 14;
    int offs[8];
    #pragma unroll
    for (int g = 0; g < 8; g++) {
        int tt = (g < 4) ? i0[lf * 4 + g] : i0[F * 4 + lf * 4 + (g - 4)];
        int kk = KS * KS;
        int c = tt / kk, r = tt - c * kk;
        int dy = r / KS, dx = r - dy * KS;
        int off;
        if (mode == 1)      off = dy * 28 + dx;              // XB 28x28, c==0
        else if (mode == 2) off = (c * 14 + dy) * 14 + dx;   // P1 padded 16x14x14
        else                off = (c * 8 + dy) * 8 + dx;     // P2 padded 48x8x8
        offs[g] = off;
    }
    ((int4*)pk)[0] = make_int4(offs[0], offs[1], offs[2], offs[3]);
    ((int4*)pk)[1] = make_int4(offs[4], offs[5], offs[6], offs[7]);
    #pragma unroll
    for (int g = 0; g < 4; g++) pk[2 + g] = softmax_coef(W0 + (lf * 4 + g) * 16);
    int a10 = i1[lf * 2 + 0], a11 = i1[lf * 2 + 1];
    int b10 = i1[F * 2 + lf * 2 + 0], b11 = i1[F * 2 + lf * 2 + 1];
    pk[6] = onehot4(a10); pk[7] = onehot4(b10);
    pk[8] = onehot4(a11); pk[9] = onehot4(b11);
    pk[10] = softmax_coef(W1 + (lf * 2 + 0) * 16);
    pk[11] = softmax_coef(W1 + (lf * 2 + 1) * 16);
    int a2 = i2[lf], b2 = i2[F + lf];
    pk[12] = make_float4(a2 == 0 ? 1.f : 0.f, a2 == 1 ? 1.f : 0.f,
                         b2 == 0 ? 1.f : 0.f, b2 == 1 ? 1.f : 0.f);
    pk[13] = softmax_coef(W2 + lf * 16);
}

// ---------------------------------------------------------------------------
// Conv stage over LDS with pre-decoded offsets.  PITCH = input row pitch,
// HP = pooled output dim, F = filters, OUTP = output padded pitch (0 = plain).
// ---------------------------------------------------------------------------
template <int PITCH, int HP, int F, int OUTP>
DEV void conv_stage(const float* Sin, float* Sout, const float4* __restrict__ pack,
                    int tid)
{
    for (int t = tid; t < F * HP * HP; t += 1024) {
        int f  = t / (HP * HP);
        int p  = t - f * (HP * HP);
        int ph = p / HP, pw = p - ph * HP;
        const float4* pk = pack + f * 14;
        int4 ao = ((const int4*)pk)[0];
        int4 bo = ((const int4*)pk)[1];
        float4 C00 = pk[2], C01 = pk[3], C02 = pk[4], C03 = pk[5];
        float4 oA0 = pk[6], oB0 = pk[7], oA1 = pk[8], oB1 = pk[9];
        float4 C10 = pk[10], C11 = pk[11], S2 = pk[12], C2 = pk[13];
        float m = -1e30f;
        #pragma unroll
        for (int dy = 0; dy < 2; dy++) {
            #pragma unroll
            for (int dx = 0; dx < 2; dx++) {
                int poff = (2 * ph + dy) * PITCH + (2 * pw + dx);
                float h00 = gev(C00, Sin[ao.x + poff], Sin[bo.x + poff]);
                float h01 = gev(C01, Sin[ao.y + poff], Sin[bo.y + poff]);
                float h02 = gev(C02, Sin[ao.z + poff], Sin[bo.z + poff]);
                float h03 = gev(C03, Sin[ao.w + poff], Sin[bo.w + poff]);
                float sa0 = fmaf(oA0.x, h00, fmaf(oA0.y, h01, fmaf(oA0.z, h02, oA0.w * h03)));
                float sb0 = fmaf(oB0.x, h00, fmaf(oB0.y, h01, fmaf(oB0.z, h02, oB0.w * h03)));
                float sa1 = fmaf(oA1.x, h00, fmaf(oA1.y, h01, fmaf(oA1.z, h02, oA1.w * h03)));
                float sb1 = fmaf(oB1.x, h00, fmaf(oB1.y, h01, fmaf(oB1.z, h02, oB1.w * h03)));
                float h10 = gev(C10, sa0, sb0);
                float h11 = gev(C11, sa1, sb1);
                float sa2 = fmaf(S2.x, h10, S2.y * h11);
                float sb2 = fmaf(S2.z, h10, S2.w * h11);
                float v = gev(C2, sa2, sb2);
                m = fmaxf(m, v);
            }
        }
        if (OUTP)
            Sout[(f * OUTP + ph + 1) * OUTP + (pw + 1)] = m;
        else
            Sout[t] = m;
    }
}

// ---------------------------------------------------------------------------
// FC stage with packed 32B records, chunk-of-5 software pipeline.
// ---------------------------------------------------------------------------
template <int DOUT, typename TIN, typename TOUT>
DEV void fc_stage(const TIN* Sin, TOUT* Sout, const float4* __restrict__ pk, int tid)
{
    constexpr int K = DOUT / 1024;   // 20 / 10 / 5
    #pragma unroll 1
    for (int k0 = 0; k0 < K; k0 += 5) {
        float4 c[5]; int ia[5], ib[5];
        #pragma unroll
        for (int j = 0; j < 5; j++) {
            int o = tid + (k0 + j) * 1024;
            c[j] = pk[2 * o];
            int4 ii = ((const int4*)pk)[2 * o + 1];
            ia[j] = ii.x; ib[j] = ii.y;
        }
        float va[5], vb[5];
        #pragma unroll
        for (int j = 0; j < 5; j++) {
            va[j] = (float)Sin[ia[j]];
            vb[j] = (float)Sin[ib[j]];
        }
        #pragma unroll
        for (int j = 0; j < 5; j++) {
            int o = tid + (k0 + j) * 1024;
            Sout[o] = (TOUT)gev(c[j], va[j], vb[j]);
        }
    }
}

// ---------------------------------------------------------------------------
// Whole network, one WG per batch element, 1024 threads.
// Aliased LDS (bytes, total 61440):
//   F1h fp16 [0,40960) | F2h fp16 [40960,61440)
//   P1p f32  [0,12544)   (16x14x14 padded; dead before fc1 writes F1h)
//   XB  f32  [12544,15680)
//   P2p f32  [40960,53248) (48x8x8 padded; dead before fc2 writes F2h)
//   P3  f32  [53248,58432) (dead before fc2)
//   F3  f32  [0,20480)     (aliases F1h, dead by fc3)
// ---------------------------------------------------------------------------
__global__ __launch_bounds__(1024, 4) void fused_net(
    const float* __restrict__ x,
    const float4* __restrict__ fcp1, const float4* __restrict__ fcp2,
    const float4* __restrict__ fcp3, const float4* __restrict__ cvp,
    float* __restrict__ out)
{
    __shared__ __align__(16) char S[61440];
    __half* F1h = (__half*)S;
    __half* F2h = (__half*)(S + 40960);
    float*  P1p = (float*)S;
    float*  XB  = (float*)(S + 12544);
    float*  P2p = (float*)(S + 40960);
    float*  P3  = (float*)(S + 53248);
    float*  F3  = (float*)S;

    const int b = blockIdx.x, tid = threadIdx.x;
    // stage 0: binarize input + zero padded buffers (borders must be 0)
    if (tid < 784) XB[tid] = x[b * 784 + tid] > 0.5f ? 1.f : 0.f;
    for (int i = tid; i < 3136; i += 1024) P1p[i] = 0.f;
    for (int i = tid; i < 3072; i += 1024) P2p[i] = 0.f;
    __syncthreads();

    conv_stage<28, 12, 16, 14>(XB, P1p, cvp + 0 * 14, tid);     // c1: 28x28 -> pool 12, pad-store 14
    __syncthreads();
    conv_stage<14, 6, 48, 8>(P1p, P2p, cvp + 16 * 14, tid);     // c2: 16x14x14 -> pool 6, pad-store 8
    __syncthreads();
    conv_stage<8, 3, 144, 0>(P2p, P3, cvp + 64 * 14, tid);      // c3: 48x8x8 -> pool 3, plain [144*9]
    __syncthreads();

    fc_stage<20480, float, __half>(P3, F1h, fcp1, tid);
    __syncthreads();
    fc_stage<10240, __half, __half>(F1h, F2h, fcp2, tid);
    __syncthreads();
    fc_stage<5120, __half, float>(F2h, F3, fcp3, tid);
    __syncthreads();

    // GroupSum: waves 0..9 each reduce one group of 512 -> out[b*10+g]
    int wave = tid >> 6, lane = tid & 63;
    if (wave < 10) {
        float s = 0.f;
        #pragma unroll
        for (int i = 0; i < 8; i++) s += F3[wave * 512 + i * 64 + lane];
        #pragma unroll
        for (int off = 32; off > 0; off >>= 1) s += __shfl_down(s, off, 64);
        if (lane == 0) out[b * 10 + wave] = s * (1.f / 30.f);
    }
}

extern "C" void kernel_launch(void* const* d_in, const int* in_sizes, int n_in,
                              void* d_out, int out_size, void* d_ws, size_t ws_size,
                              hipStream_t stream)
{
    const float* x     = (const float*)d_in[0];
    const int*   c1i0  = (const int*)d_in[1];  const float* c1w0 = (const float*)d_in[2];
    const int*   c1i1  = (const int*)d_in[3];  const float* c1w1 = (const float*)d_in[4];
    const int*   c1i2  = (const int*)d_in[5];  const float* c1w2 = (const float*)d_in[6];
    const int*   c2i0  = (const int*)d_in[7];  const float* c2w0 = (const float*)d_in[8];
    const int*   c2i1  = (const int*)d_in[9];  const float* c2w1 = (const float*)d_in[10];
    const int*   c2i2  = (const int*)d_in[11]; const float* c2w2 = (const float*)d_in[12];
    const int*   c3i0  = (const int*)d_in[13]; const float* c3w0 = (const float*)d_in[14];
    const int*   c3i1  = (const int*)d_in[15]; const float* c3w1 = (const float*)d_in[16];
    const int*   c3i2  = (const int*)d_in[17]; const float* c3w2 = (const float*)d_in[18];
    const int*   fc1i  = (const int*)d_in[19]; const float* fc1w = (const float*)d_in[20];
    const int*   fc2i  = (const int*)d_in[21]; const float* fc2w = (const float*)d_in[22];
    const int*   fc3i  = (const int*)d_in[23]; const float* fc3w = (const float*)d_in[24];

    // ws: fcp1 @0 (20480*32B=655360) | fcp2 @655360 (327680) | fcp3 @983040
    //     (163840) | convpack @1146880 (208*224=46592)  -> end 1193472 B
    char* ws = (char*)d_ws;
    float4* fcp1 = (float4*)ws;
    float4* fcp2 = (float4*)(ws + 655360);
    float4* fcp3 = (float4*)(ws + 983040);
    float4* cvp  = (float4*)(ws + 1146880);

    setup_kernel<<<141, 256, 0, stream>>>(
        c1i0, c1i1, c1i2, c2i0, c2i1, c2i2, c3i0, c3i1, c3i2,
        c1w0, c1w1, c1w2, c2w0, c2w1, c2w2, c3w0, c3w1, c3w2,
        fc1i, fc1w, fc2i, fc2w, fc3i, fc3w,
        fcp1, fcp2, fcp3, cvp);

    fused_net<<<100, 1024, 0, stream>>>(
        x, fcp1, fcp2, fcp3, cvp, (float*)d_out);
}